// Round 4
// baseline (351.606 us; speedup 1.0000x reference)
//
#include <hip/hip_runtime.h>
#include <cstdint>
#include <cstddef>

#define C_CH 128
#define T_TOK 9216
#define H_IMG 96
#define W_IMG 96
#define NSTATE 8

// fused scan tiling: 64 output tokens, 32-token warm-up halo each direction.
#define CHUNK 64
#define RHALO 32
#define REGION (CHUNK + 2 * RHALO)   // 128

__device__ __forceinline__ float siluf_dev(float x) {
  return x / (1.0f + expf(-x));
}

__device__ __forceinline__ float fast_silu(float x) {
  // x * sigmoid(x) with native rcp; binary-thresholded output tolerates ~2ulp
  return __fdividef(x, 1.0f + __expf(-x));
}

// ---------------------------------------------------------------------------
// K0: slot assignment from record_len (int32!) + v = out_proj_w @ mlp_w
// ---------------------------------------------------------------------------
__global__ __launch_bounds__(128) void k0_setup(
    const int* __restrict__ rec, int n_groups, int N,
    const float* __restrict__ out_proj_w, const float* __restrict__ mlp_w,
    float* __restrict__ vvec, int* __restrict__ slot)
{
  const int tid = threadIdx.x;
  if (tid == 0) {
    int f = 0, sl = 0;
    for (int g = 0; g < n_groups; ++g) {
      const int L = rec[g];
      slot[f] = -1;                       // ego / single frame -> mask = 1
      for (int i = 1; i < L; ++i) slot[f + i] = sl++;
      f += L;
    }
  }
  if (tid < C_CH) {
    float acc = 0.0f;
    for (int j = 0; j < C_CH; ++j) acc += out_proj_w[tid * C_CH + j] * mlp_w[j];
    vvec[tid] = acc;
  }
}

// ---------------------------------------------------------------------------
// K1: rmsnorm + xz = xn @ in_proj  (M=64 token tile, K=128, N=256 in 4 chunks)
//     writes xi_pre[t][c], w[t][c] = 0.5*silu(z)*v[c], logit_init[t]
// R4: Bsm removed — B streamed from global (16 lanes/tc share an address ->
//     HW broadcast; in_proj 128KB is L2-hot). rms_w folded into Asm as
//     (val*ir)*rw (1-ulp assoc change vs staged-B fold). LDS 66->34.5 KB ->
//     4 blocks/CU (was 2); syncs 10 -> 4.
// ---------------------------------------------------------------------------
__global__ __launch_bounds__(256, 4) void k1_gemm(
    const float* __restrict__ feats, const float* __restrict__ in_proj,
    const float* __restrict__ rms_w, const float* __restrict__ mlp_w,
    const float* __restrict__ mlp_b, const float* __restrict__ vvec,
    const int* __restrict__ slot,
    float* __restrict__ xipre, float* __restrict__ wbuf,
    float* __restrict__ logit)
{
  __shared__ float Asm[C_CH * 64];   // A[k][t]  (raw x, then ir*rw-scaled)
  __shared__ float redA[256], redB[256], irS[64];
  const int f = blockIdx.y;
  const int s = slot[f];
  if (s < 0) return;
  const int m0 = blockIdx.x * 64;
  const int tid = threadIdx.x;

  // stage A: x[c][t], coalesced along t
  {
    const int c0 = tid >> 4;
    const int tq = (tid & 15) * 4;
    const float* src = feats + (size_t)f * C_CH * T_TOK + m0 + tq;
    #pragma unroll
    for (int i = 0; i < 8; ++i) {
      const int c = c0 + i * 16;
      const float4 x4 = *(const float4*)(src + (size_t)c * T_TOK);
      *(float4*)&Asm[c * 64 + tq] = x4;
    }
  }
  __syncthreads();
  // pre-pass: per-token rms + logit init (res . mlp_w + b), 4 threads/token
  {
    const int t = tid & 63;
    const int q = tid >> 6;
    float ssum = 0.0f, rm = 0.0f;
    for (int cc = q * 32; cc < q * 32 + 32; ++cc) {
      const float val = Asm[cc * 64 + t];
      ssum += val * val;
      rm += val * mlp_w[cc];
    }
    redA[tid] = ssum; redB[tid] = rm;
  }
  __syncthreads();
  if (tid < 64) {
    const int t = tid;
    const float ssum = redA[t] + redA[t + 64] + redA[t + 128] + redA[t + 192];
    const float rm   = redB[t] + redB[t + 64] + redB[t + 128] + redB[t + 192];
    const float ir = 1.0f / sqrtf(ssum * (1.0f / C_CH) + 1e-5f);
    logit[(size_t)s * T_TOK + m0 + t] = rm + mlp_b[0];
    irS[t] = ir;
  }
  __syncthreads();
  {
    const int t = tid & 63;
    const int q = tid >> 6;
    const float ir = irS[t];
    for (int cc = q * 32; cc < q * 32 + 32; ++cc)
      Asm[cc * 64 + t] = (Asm[cc * 64 + t] * ir) * rms_w[cc];
  }
  __syncthreads();

  const int ti = tid >> 4;   // 0..15 -> rows ti*4..+3
  const int tc = tid & 15;   // 0..15 -> cols tc*4..+3
  for (int chunk = 0; chunk < 4; ++chunk) {
    const int n0 = chunk * 64;
    const float* bp = in_proj + n0 + tc * 4;
    float acc[4][4];
    #pragma unroll
    for (int i = 0; i < 4; ++i)
      #pragma unroll
      for (int j = 0; j < 4; ++j) acc[i][j] = 0.0f;
    #pragma unroll 8
    for (int k = 0; k < C_CH; ++k) {
      const float4 a4 = *(const float4*)&Asm[k * 64 + ti * 4];
      const float4 b4 = *(const float4*)(bp + (size_t)k * 256);
      acc[0][0] += a4.x * b4.x; acc[0][1] += a4.x * b4.y; acc[0][2] += a4.x * b4.z; acc[0][3] += a4.x * b4.w;
      acc[1][0] += a4.y * b4.x; acc[1][1] += a4.y * b4.y; acc[1][2] += a4.y * b4.z; acc[1][3] += a4.y * b4.w;
      acc[2][0] += a4.z * b4.x; acc[2][1] += a4.z * b4.y; acc[2][2] += a4.z * b4.z; acc[2][3] += a4.z * b4.w;
      acc[3][0] += a4.w * b4.x; acc[3][1] += a4.w * b4.y; acc[3][2] += a4.w * b4.z; acc[3][3] += a4.w * b4.w;
    }
    if (chunk < 2) {
      const int cb = n0 + tc * 4;     // xi channel 0..127
      #pragma unroll
      for (int i = 0; i < 4; ++i) {
        const int t = m0 + ti * 4 + i;
        float4 o; o.x = acc[i][0]; o.y = acc[i][1]; o.z = acc[i][2]; o.w = acc[i][3];
        *(float4*)&xipre[((size_t)s * T_TOK + t) * C_CH + cb] = o;
      }
    } else {
      const int zc = (chunk - 2) * 64 + tc * 4;  // z channel 0..127
      const float4 v4 = *(const float4*)&vvec[zc];
      #pragma unroll
      for (int i = 0; i < 4; ++i) {
        const int t = m0 + ti * 4 + i;
        float4 o;
        o.x = 0.5f * siluf_dev(acc[i][0]) * v4.x;
        o.y = 0.5f * siluf_dev(acc[i][1]) * v4.y;
        o.z = 0.5f * siluf_dev(acc[i][2]) * v4.z;
        o.w = 0.5f * siluf_dev(acc[i][3]) * v4.w;
        *(float4*)&wbuf[((size_t)s * T_TOK + t) * C_CH + zc] = o;
      }
    }
  }
}

// ---------------------------------------------------------------------------
// K2: conv+silu+projection -> dbl_g[t][24] (dt|B|C), full lane efficiency.
// ---------------------------------------------------------------------------
__global__ __launch_bounds__(256, 4) void k2_convproj(
    const float* __restrict__ xipre,
    const float* __restrict__ conv_w, const float* __restrict__ conv_b,
    const float* __restrict__ x_proj_w, const int* __restrict__ slot,
    float* __restrict__ dbl_g)
{
  __shared__ float xibuf[64 * 129];   // 33 KB
  const int f = blockIdx.y;
  const int s = slot[f];
  if (s < 0) return;
  const int m0 = blockIdx.x * 64;
  const int tid = threadIdx.x;
  const int c = tid & 127;
  const int half = tid >> 7;
  const size_t rowbase = (size_t)s * T_TOK;
  const float4 cw = *(const float4*)(conv_w + c * 4);
  const float cb = conv_b[c];

  auto ldx = [&](int t) -> float {
    return (t >= 0) ? xipre[(rowbase + t) * C_CH + c] : 0.0f;   // t < T always here
  };

  {
    const int t0 = m0 + half * 32;
    float xm1 = ldx(t0 - 1), xm2 = ldx(t0 - 2), xm3 = ldx(t0 - 3);
    #pragma unroll
    for (int i = 0; i < 32; ++i) {
      const float cur = ldx(t0 + i);
      const float sum = cw.x * xm3 + cw.y * xm2 + cw.z * xm1 + cw.w * cur + cb;
      xibuf[(half * 32 + i) * 129 + c] = fast_silu(sum);
      xm3 = xm2; xm2 = xm1; xm1 = cur;
    }
  }
  __syncthreads();
  {
    const int q6 = __builtin_amdgcn_readfirstlane(tid >> 6) * 6;  // wave's out base
    const int tok = tid & 63;
    float acc[6] = {0, 0, 0, 0, 0, 0};
    for (int cc = 0; cc < C_CH; ++cc) {
      const float xv = xibuf[tok * 129 + cc];
      #pragma unroll
      for (int jj = 0; jj < 6; ++jj)
        acc[jj] += xv * x_proj_w[cc * 24 + q6 + jj];   // scalar (uniform idx)
    }
    #pragma unroll
    for (int jj = 0; jj < 6; ++jj)
      dbl_g[(rowbase + m0 + tok) * 24 + q6 + jj] = acc[jj];
  }
}

// ---------------------------------------------------------------------------
// K3_scan: bidirectional chunked scan, direction-split + software-pipelined.
// Block = 128 threads (2 waves) = one direction of one 64-token chunk;
// grid z = {0:fwd, 1:bwd}. 2016 active blocks, LDS 12.3 KB -> ~8 blocks/CU.
// Per 8-step group the 16 xipre/wbuf loads are double-buffered (pgA/pgB
// named arrays, macro-unrolled -> registers): group g+1's loads issue before
// group g's compute, hiding L2/L3 latency under ~1200 cyc of scan math.
// Arithmetic order identical to R3 -> bit-identical logits.
// ---------------------------------------------------------------------------
__global__ __launch_bounds__(128, 4) void k3_scan(
    const float* __restrict__ xipre, const float* __restrict__ wbuf,
    const float* __restrict__ dbl_g,
    const float* __restrict__ conv_w, const float* __restrict__ conv_b,
    const float* __restrict__ dt_proj_w, const float* __restrict__ dt_proj_b,
    const float* __restrict__ A_log_f, const float* __restrict__ A_log_b,
    const float* __restrict__ D_f, const float* __restrict__ D_b,
    const int* __restrict__ slot, float* __restrict__ logit)
{
  __shared__ float dbl[REGION * 24];      // 12.3 KB [region_row][0:8=dt 8:16=B 16:24=C]
  const int f = blockIdx.y;
  const int s = slot[f];
  if (s < 0) return;
  const int c0 = blockIdx.x * CHUNK;
  const int r0 = c0 - RHALO;              // region start (may be negative)
  const int tid = threadIdx.x;            // 0..127
  const int c = tid;                      // channel
  const int half = blockIdx.z;            // 0 = fwd, 1 = bwd
  const size_t rowbase = (size_t)s * T_TOK;
  const float4 cw = *(const float4*)(conv_w + c * 4);
  const float cb = conv_b[c];

  auto ldx = [&](int t) -> float {
    return (t >= 0 && t < T_TOK) ? xipre[(rowbase + t) * C_CH + c] : 0.0f;
  };

  // ---- stage dbl region slice: 128 rows x 24 floats = 768 float4 ----
  {
    const long grow = ((long)rowbase + r0) * 24;
    const int lo  = (r0 < 0) ? (-r0) * 6 : 0;
    const int hi  = (r0 + REGION > T_TOK) ? (T_TOK - r0) * 6 : REGION * 6;
    #pragma unroll
    for (int i = 0; i < 6; ++i) {
      const int idx = tid + i * 128;
      if (idx >= lo && idx < hi)
        *(float4*)&dbl[idx * 4] = *(const float4*)&dbl_g[grow + (long)idx * 4];
    }
  }
  __syncthreads();

  // ---- Scan setup ----
  float dw[8], Ac[8];
  const float* Alog = half ? A_log_b : A_log_f;
  #pragma unroll
  for (int r = 0; r < 8; ++r) dw[r] = dt_proj_w[r * C_CH + c];
  #pragma unroll
  for (int n = 0; n < NSTATE; ++n) Ac[n] = -expf(Alog[c * NSTATE + n]);
  const float bias = dt_proj_b[c];
  const float Dd = half ? D_b[c] : D_f[c];
  float h[8] = {0, 0, 0, 0, 0, 0, 0, 0};

  // fast-decay eligibility: Ac[n] == (n+1)*Ac[0] (holds for this problem's A)
  const float a0 = Ac[0];
  int okl = 1;
  #pragma unroll
  for (int n = 1; n < NSTATE; ++n)
    okl &= (fabsf(Ac[n] - (float)(n + 1) * a0) <= 1e-4f * fabsf(Ac[n])) ? 1 : 0;
  const bool fastA = (__all(okl) != 0);   // wave-uniform

  auto decay8 = [&](float dlt, float* dA) {
    if (fastA) {
      const float e1 = __expf(dlt * a0);
      const float e2 = e1 * e1, e3 = e2 * e1, e4 = e2 * e2;
      dA[0] = e1; dA[1] = e2; dA[2] = e3; dA[3] = e4;
      dA[4] = e4 * e1; dA[5] = e4 * e2; dA[6] = e4 * e3; dA[7] = e4 * e4;
    } else {
      #pragma unroll
      for (int n = 0; n < NSTATE; ++n) dA[n] = __expf(dlt * Ac[n]);
    }
  };

#define SCAN_CORE(P_, XIV_, OUT_, WGJ_, T_) do {                              \
    const float4 d0 = *(const float4*)&dbl[(P_) * 24];                        \
    const float4 d1 = *(const float4*)&dbl[(P_) * 24 + 4];                    \
    float pre = bias;                                                         \
    pre += d0.x * dw[0] + d0.y * dw[1] + d0.z * dw[2] + d0.w * dw[3];         \
    pre += d1.x * dw[4] + d1.y * dw[5] + d1.z * dw[6] + d1.w * dw[7];         \
    const float dlt = fmaxf(pre, 0.0f) + __logf(1.0f + __expf(-fabsf(pre)));  \
    const float u = dlt * (XIV_);                                             \
    const float4 b0 = *(const float4*)&dbl[(P_) * 24 + 8];                    \
    const float4 b1 = *(const float4*)&dbl[(P_) * 24 + 12];                   \
    float dA[8];                                                              \
    decay8(dlt, dA);                                                          \
    h[0] = dA[0] * h[0] + u * b0.x;                                           \
    h[1] = dA[1] * h[1] + u * b0.y;                                           \
    h[2] = dA[2] * h[2] + u * b0.z;                                           \
    h[3] = dA[3] * h[3] + u * b0.w;                                           \
    h[4] = dA[4] * h[4] + u * b1.x;                                           \
    h[5] = dA[5] * h[5] + u * b1.y;                                           \
    h[6] = dA[6] * h[6] + u * b1.z;                                           \
    h[7] = dA[7] * h[7] + u * b1.w;                                           \
    if (OUT_) {                                                               \
      const float4 cc0 = *(const float4*)&dbl[(P_) * 24 + 16];                \
      const float4 cc1 = *(const float4*)&dbl[(P_) * 24 + 20];                \
      float y = (XIV_) * Dd;                                                  \
      y += h[0] * cc0.x + h[1] * cc0.y + h[2] * cc0.z + h[3] * cc0.w;         \
      y += h[4] * cc1.x + h[5] * cc1.y + h[6] * cc1.z + h[7] * cc1.w;         \
      float contrib = y * (WGJ_);                                             \
      contrib += __shfl_xor(contrib, 1);                                      \
      contrib += __shfl_xor(contrib, 2);                                      \
      contrib += __shfl_xor(contrib, 4);                                      \
      contrib += __shfl_xor(contrib, 8);                                      \
      contrib += __shfl_xor(contrib, 16);                                     \
      contrib += __shfl_xor(contrib, 32);                                     \
      if ((tid & 63) == 0) atomicAdd(&logit[rowbase + (T_)], contrib);        \
    } } while (0)

  if (half == 0) {
    // ---- forward: t from tb to c0+CHUNK-1, pipelined 8-step groups ----
    const int tb = (r0 < 0) ? 0 : r0;
    const int outg0 = (c0 - tb) >> 3;        // 0 or 4
    const int ng = (c0 + CHUNK - tb) >> 3;   // 8 or 12 (always even)
    float xm1 = ldx(tb - 1), xm2 = ldx(tb - 2), xm3 = ldx(tb - 3);
    float pgA[8], wgA[8], pgB[8], wgB[8];

#define LOADF(G, PG, WG) do {                                                 \
    const int t0_ = tb + (G) * 8;                                             \
    const bool out_ = ((G) >= outg0);                                         \
    _Pragma("unroll")                                                         \
    for (int j = 0; j < 8; ++j) {                                             \
      const size_t gi = (rowbase + t0_ + j) * C_CH + c;                       \
      PG[j] = xipre[gi];                                                      \
      WG[j] = out_ ? wbuf[gi] : 0.0f;                                         \
    } } while (0)

#define STEPSF(G, PG, WG) do {                                                \
    const int t0_ = tb + (G) * 8;                                             \
    const bool out_ = ((G) >= outg0);                                         \
    _Pragma("unroll")                                                         \
    for (int j = 0; j < 8; ++j) {                                             \
      const int t = t0_ + j;                                                  \
      const int p = t - r0;                                                   \
      const float cur = PG[j];                                                \
      const float sum = cw.x * xm3 + cw.y * xm2 + cw.z * xm1 + cw.w * cur + cb; \
      const float xiv = fast_silu(sum);                                       \
      xm3 = xm2; xm2 = xm1; xm1 = cur;                                        \
      SCAN_CORE(p, xiv, out_, WG[j], t);                                      \
    } } while (0)

    LOADF(0, pgA, wgA);
    for (int g = 0; g < ng; g += 2) {
      LOADF(g + 1, pgB, wgB);
      STEPSF(g, pgA, wgA);
      if (g + 2 < ng) LOADF(g + 2, pgA, wgA);
      STEPSF(g + 1, pgB, wgB);
    }
  } else {
    // ---- backward: t from te2-1 down to c0, pipelined 8-step groups ----
    const int te2e = r0 + REGION;
    const int te2 = (te2e > T_TOK) ? T_TOK : te2e;
    const int outg0 = (te2 - (c0 + CHUNK)) >> 3;  // 0 or 4
    const int ng = (te2 - c0) >> 3;               // 8 or 12 (always even)
    float w0 = ldx(te2 - 1), w1 = ldx(te2 - 2), w2 = ldx(te2 - 3), w3 = ldx(te2 - 4);
    float pgA[8], wgA[8], pgB[8], wgB[8];

#define LOADB(G, NV, WG) do {                                                 \
    const int t0_ = te2 - 1 - (G) * 8;                                        \
    const bool out_ = ((G) >= outg0);                                         \
    _Pragma("unroll")                                                         \
    for (int j = 0; j < 8; ++j) {                                             \
      NV[j] = ldx(t0_ - 4 - j);                                               \
      WG[j] = out_ ? wbuf[(rowbase + t0_ - j) * C_CH + c] : 0.0f;             \
    } } while (0)

#define STEPSB(G, NV, WG) do {                                                \
    const int t0_ = te2 - 1 - (G) * 8;                                        \
    const bool out_ = ((G) >= outg0);                                         \
    _Pragma("unroll")                                                         \
    for (int j = 0; j < 8; ++j) {                                             \
      const int t = t0_ - j;                                                  \
      const int p = t - r0;                                                   \
      const float sum = cw.x * w3 + cw.y * w2 + cw.z * w1 + cw.w * w0 + cb;   \
      const float xiv = fast_silu(sum);                                       \
      w0 = w1; w1 = w2; w2 = w3; w3 = NV[j];                                  \
      SCAN_CORE(p, xiv, out_, WG[j], t);                                      \
    } } while (0)

    LOADB(0, pgA, wgA);
    for (int g = 0; g < ng; g += 2) {
      LOADB(g + 1, pgB, wgB);
      STEPSB(g, pgA, wgA);
      if (g + 2 < ng) LOADB(g + 2, pgA, wgA);
      STEPSB(g + 1, pgB, wgB);
    }
  }
#undef SCAN_CORE
#undef LOADF
#undef STEPSF
#undef LOADB
#undef STEPSB
}

// ---------------------------------------------------------------------------
// K4: threshold (sigmoid(lg)>0.5 <=> lg>0, exact) + 3x3 max pool. ego -> 1.
// ---------------------------------------------------------------------------
__global__ __launch_bounds__(128) void k4_pool(
    const float* __restrict__ logit, const int* __restrict__ slot,
    float* __restrict__ out)
{
  const int w = threadIdx.x;
  if (w >= W_IMG) return;
  const int hh = blockIdx.x;
  const int f = blockIdx.y;
  const int s = slot[f];
  float m = 0.0f;
  if (s < 0) {
    m = 1.0f;
  } else {
    for (int dh = -1; dh <= 1; ++dh) {
      const int h2 = hh + dh;
      if (h2 < 0 || h2 >= H_IMG) continue;
      for (int dw = -1; dw <= 1; ++dw) {
        const int w2 = w + dw;
        if (w2 < 0 || w2 >= W_IMG) continue;
        if (logit[(size_t)s * T_TOK + h2 * W_IMG + w2] > 0.0f) m = 1.0f;
      }
    }
  }
  out[(size_t)f * T_TOK + hh * W_IMG + w] = m;
}

// ---------------------------------------------------------------------------
extern "C" void kernel_launch(void* const* d_in, const int* in_sizes, int n_in,
                              void* d_out, int out_size, void* d_ws, size_t ws_size,
                              hipStream_t stream) {
  const float* feats      = (const float*)d_in[0];
  const float* in_proj    = (const float*)d_in[1];
  const float* conv_w     = (const float*)d_in[2];
  const float* conv_b     = (const float*)d_in[3];
  const float* x_proj_w   = (const float*)d_in[4];
  const float* dt_proj_w  = (const float*)d_in[5];
  const float* dt_proj_b  = (const float*)d_in[6];
  const float* A_log_f    = (const float*)d_in[7];
  const float* A_log_b    = (const float*)d_in[8];
  const float* D_f        = (const float*)d_in[9];
  const float* D_b        = (const float*)d_in[10];
  const float* out_proj_w = (const float*)d_in[11];
  const float* rms_w      = (const float*)d_in[12];
  const float* mlp_w      = (const float*)d_in[13];
  const float* mlp_b      = (const float*)d_in[14];
  const int*   rec        = (const int*)d_in[15];   // int32! (jax downcasts int64)

  const int N = in_sizes[0] / (C_CH * T_TOK);
  const int n_groups = in_sizes[15];
  int S = N - n_groups;
  if (S < 1) S = 1;

  // workspace carve-up
  char* p = (char*)d_ws;
  float* vvec  = (float*)p; p += 1024;
  int*   slot  = (int*)p;   p += ((N * 4 + 255) / 256) * 256;
  float* logit = (float*)p; p += (size_t)S * T_TOK * 4;
  float* xipre = (float*)p; p += (size_t)S * T_TOK * C_CH * 4;
  float* wA    = (float*)p; p += (size_t)S * T_TOK * C_CH * 4;
  float* dblg  = (float*)p; p += (size_t)S * T_TOK * 24 * 4;
  (void)ws_size; (void)n_in; (void)out_size;

  k0_setup<<<1, 128, 0, stream>>>(rec, n_groups, N, out_proj_w, mlp_w, vvec, slot);
  k1_gemm<<<dim3(T_TOK / 64, N), 256, 0, stream>>>(
      feats, in_proj, rms_w, mlp_w, mlp_b, vvec, slot, xipre, wA, logit);
  k2_convproj<<<dim3(T_TOK / 64, N), 256, 0, stream>>>(
      xipre, conv_w, conv_b, x_proj_w, slot, dblg);
  k3_scan<<<dim3(T_TOK / CHUNK, N, 2), 128, 0, stream>>>(
      xipre, wA, dblg, conv_w, conv_b, dt_proj_w, dt_proj_b,
      A_log_f, A_log_b, D_f, D_b, slot, logit);
  k4_pool<<<dim3(H_IMG, N), 128, 0, stream>>>(logit, slot, (float*)d_out);
}

// Round 5
// 346.704 us; speedup vs baseline: 1.0141x; 1.0141x over previous
//
#include <hip/hip_runtime.h>
#include <cstdint>
#include <cstddef>

#define C_CH 128
#define T_TOK 9216
#define H_IMG 96
#define W_IMG 96
#define NSTATE 8

// fused scan tiling: 32 output tokens, 32-token warm-up halo each direction.
// CHUNK=32: steps/wave 96->64, blocks 1008->2016 -> 8 blocks/CU x 4 waves =
// 32 waves/CU (full machine). Latency-bound scan => dur ~ steps/block.
#define CHUNK 32
#define RHALO 32
#define REGION (CHUNK + 2 * RHALO)   // 96

__device__ __forceinline__ float siluf_dev(float x) {
  return x / (1.0f + expf(-x));
}

__device__ __forceinline__ float fast_silu(float x) {
  // x * sigmoid(x) with native rcp; binary-thresholded output tolerates ~2ulp
  return __fdividef(x, 1.0f + __expf(-x));
}

// ---------------------------------------------------------------------------
// K0: slot assignment from record_len (int32!) + v = out_proj_w @ mlp_w
// ---------------------------------------------------------------------------
__global__ __launch_bounds__(128) void k0_setup(
    const int* __restrict__ rec, int n_groups, int N,
    const float* __restrict__ out_proj_w, const float* __restrict__ mlp_w,
    float* __restrict__ vvec, int* __restrict__ slot)
{
  const int tid = threadIdx.x;
  if (tid == 0) {
    int f = 0, sl = 0;
    for (int g = 0; g < n_groups; ++g) {
      const int L = rec[g];
      slot[f] = -1;                       // ego / single frame -> mask = 1
      for (int i = 1; i < L; ++i) slot[f + i] = sl++;
      f += L;
    }
  }
  if (tid < C_CH) {
    float acc = 0.0f;
    for (int j = 0; j < C_CH; ++j) acc += out_proj_w[tid * C_CH + j] * mlp_w[j];
    vvec[tid] = acc;
  }
}

// ---------------------------------------------------------------------------
// K1: rmsnorm + xz = xn @ in_proj  (M=64 token tile, K=128, N=256 in 4 chunks)
//     writes xi_pre[t][c], w[t][c] = 0.5*silu(z)*v[c], logit_init[t]
// B streamed from global (16 lanes/tc share an address -> HW broadcast;
// in_proj 128KB is L2-hot). rms_w folded into Asm. LDS 34.5 KB, 4 blocks/CU.
// ---------------------------------------------------------------------------
__global__ __launch_bounds__(256, 4) void k1_gemm(
    const float* __restrict__ feats, const float* __restrict__ in_proj,
    const float* __restrict__ rms_w, const float* __restrict__ mlp_w,
    const float* __restrict__ mlp_b, const float* __restrict__ vvec,
    const int* __restrict__ slot,
    float* __restrict__ xipre, float* __restrict__ wbuf,
    float* __restrict__ logit)
{
  __shared__ float Asm[C_CH * 64];   // A[k][t]  (raw x, then ir*rw-scaled)
  __shared__ float redA[256], redB[256], irS[64];
  const int f = blockIdx.y;
  const int s = slot[f];
  if (s < 0) return;
  const int m0 = blockIdx.x * 64;
  const int tid = threadIdx.x;

  // stage A: x[c][t], coalesced along t
  {
    const int c0 = tid >> 4;
    const int tq = (tid & 15) * 4;
    const float* src = feats + (size_t)f * C_CH * T_TOK + m0 + tq;
    #pragma unroll
    for (int i = 0; i < 8; ++i) {
      const int c = c0 + i * 16;
      const float4 x4 = *(const float4*)(src + (size_t)c * T_TOK);
      *(float4*)&Asm[c * 64 + tq] = x4;
    }
  }
  __syncthreads();
  // pre-pass: per-token rms + logit init (res . mlp_w + b), 4 threads/token
  {
    const int t = tid & 63;
    const int q = tid >> 6;
    float ssum = 0.0f, rm = 0.0f;
    for (int cc = q * 32; cc < q * 32 + 32; ++cc) {
      const float val = Asm[cc * 64 + t];
      ssum += val * val;
      rm += val * mlp_w[cc];
    }
    redA[tid] = ssum; redB[tid] = rm;
  }
  __syncthreads();
  if (tid < 64) {
    const int t = tid;
    const float ssum = redA[t] + redA[t + 64] + redA[t + 128] + redA[t + 192];
    const float rm   = redB[t] + redB[t + 64] + redB[t + 128] + redB[t + 192];
    const float ir = 1.0f / sqrtf(ssum * (1.0f / C_CH) + 1e-5f);
    logit[(size_t)s * T_TOK + m0 + t] = rm + mlp_b[0];
    irS[t] = ir;
  }
  __syncthreads();
  {
    const int t = tid & 63;
    const int q = tid >> 6;
    const float ir = irS[t];
    for (int cc = q * 32; cc < q * 32 + 32; ++cc)
      Asm[cc * 64 + t] = (Asm[cc * 64 + t] * ir) * rms_w[cc];
  }
  __syncthreads();

  const int ti = tid >> 4;   // 0..15 -> rows ti*4..+3
  const int tc = tid & 15;   // 0..15 -> cols tc*4..+3
  for (int chunk = 0; chunk < 4; ++chunk) {
    const int n0 = chunk * 64;
    const float* bp = in_proj + n0 + tc * 4;
    float acc[4][4];
    #pragma unroll
    for (int i = 0; i < 4; ++i)
      #pragma unroll
      for (int j = 0; j < 4; ++j) acc[i][j] = 0.0f;
    #pragma unroll 8
    for (int k = 0; k < C_CH; ++k) {
      const float4 a4 = *(const float4*)&Asm[k * 64 + ti * 4];
      const float4 b4 = *(const float4*)(bp + (size_t)k * 256);
      acc[0][0] += a4.x * b4.x; acc[0][1] += a4.x * b4.y; acc[0][2] += a4.x * b4.z; acc[0][3] += a4.x * b4.w;
      acc[1][0] += a4.y * b4.x; acc[1][1] += a4.y * b4.y; acc[1][2] += a4.y * b4.z; acc[1][3] += a4.y * b4.w;
      acc[2][0] += a4.z * b4.x; acc[2][1] += a4.z * b4.y; acc[2][2] += a4.z * b4.z; acc[2][3] += a4.z * b4.w;
      acc[3][0] += a4.w * b4.x; acc[3][1] += a4.w * b4.y; acc[3][2] += a4.w * b4.z; acc[3][3] += a4.w * b4.w;
    }
    if (chunk < 2) {
      const int cb = n0 + tc * 4;     // xi channel 0..127
      #pragma unroll
      for (int i = 0; i < 4; ++i) {
        const int t = m0 + ti * 4 + i;
        float4 o; o.x = acc[i][0]; o.y = acc[i][1]; o.z = acc[i][2]; o.w = acc[i][3];
        *(float4*)&xipre[((size_t)s * T_TOK + t) * C_CH + cb] = o;
      }
    } else {
      const int zc = (chunk - 2) * 64 + tc * 4;  // z channel 0..127
      const float4 v4 = *(const float4*)&vvec[zc];
      #pragma unroll
      for (int i = 0; i < 4; ++i) {
        const int t = m0 + ti * 4 + i;
        float4 o;
        o.x = 0.5f * siluf_dev(acc[i][0]) * v4.x;
        o.y = 0.5f * siluf_dev(acc[i][1]) * v4.y;
        o.z = 0.5f * siluf_dev(acc[i][2]) * v4.z;
        o.w = 0.5f * siluf_dev(acc[i][3]) * v4.w;
        *(float4*)&wbuf[((size_t)s * T_TOK + t) * C_CH + zc] = o;
      }
    }
  }
}

// ---------------------------------------------------------------------------
// K2: conv+silu+projection -> dbl_g[t][24] (dt|B|C), full lane efficiency.
// ---------------------------------------------------------------------------
__global__ __launch_bounds__(256, 4) void k2_convproj(
    const float* __restrict__ xipre,
    const float* __restrict__ conv_w, const float* __restrict__ conv_b,
    const float* __restrict__ x_proj_w, const int* __restrict__ slot,
    float* __restrict__ dbl_g)
{
  __shared__ float xibuf[64 * 129];   // 33 KB
  const int f = blockIdx.y;
  const int s = slot[f];
  if (s < 0) return;
  const int m0 = blockIdx.x * 64;
  const int tid = threadIdx.x;
  const int c = tid & 127;
  const int half = tid >> 7;
  const size_t rowbase = (size_t)s * T_TOK;
  const float4 cw = *(const float4*)(conv_w + c * 4);
  const float cb = conv_b[c];

  auto ldx = [&](int t) -> float {
    return (t >= 0) ? xipre[(rowbase + t) * C_CH + c] : 0.0f;   // t < T always here
  };

  {
    const int t0 = m0 + half * 32;
    float xm1 = ldx(t0 - 1), xm2 = ldx(t0 - 2), xm3 = ldx(t0 - 3);
    #pragma unroll
    for (int i = 0; i < 32; ++i) {
      const float cur = ldx(t0 + i);
      const float sum = cw.x * xm3 + cw.y * xm2 + cw.z * xm1 + cw.w * cur + cb;
      xibuf[(half * 32 + i) * 129 + c] = fast_silu(sum);
      xm3 = xm2; xm2 = xm1; xm1 = cur;
    }
  }
  __syncthreads();
  {
    const int q6 = __builtin_amdgcn_readfirstlane(tid >> 6) * 6;  // wave's out base
    const int tok = tid & 63;
    float acc[6] = {0, 0, 0, 0, 0, 0};
    for (int cc = 0; cc < C_CH; ++cc) {
      const float xv = xibuf[tok * 129 + cc];
      #pragma unroll
      for (int jj = 0; jj < 6; ++jj)
        acc[jj] += xv * x_proj_w[cc * 24 + q6 + jj];   // scalar (uniform idx)
    }
    #pragma unroll
    for (int jj = 0; jj < 6; ++jj)
      dbl_g[(rowbase + m0 + tok) * 24 + q6 + jj] = acc[jj];
  }
}

// ---------------------------------------------------------------------------
// K3_scan: bidirectional chunked scan ONLY. Block = 256 threads = one
// 32-token chunk, waves 0-1 fwd / waves 2-3 bwd (R3 structure, reverted from
// the R4 direction-split which doubled staging and regressed).
// Region = [c0-32, c0+64): 64 scan steps per direction (32 halo + 32 out).
// 2016 active blocks x 4 waves = full 32-wave/CU machine; LDS 9.2 KB;
// launch_bounds(256,8) caps VGPR at 64 (compiler used 44 in this structure).
// Arithmetic order identical to R3 -> bit-identical logits.
// ---------------------------------------------------------------------------
__global__ __launch_bounds__(256, 8) void k3_scan(
    const float* __restrict__ xipre, const float* __restrict__ wbuf,
    const float* __restrict__ dbl_g,
    const float* __restrict__ conv_w, const float* __restrict__ conv_b,
    const float* __restrict__ dt_proj_w, const float* __restrict__ dt_proj_b,
    const float* __restrict__ A_log_f, const float* __restrict__ A_log_b,
    const float* __restrict__ D_f, const float* __restrict__ D_b,
    const int* __restrict__ slot, float* __restrict__ logit)
{
  __shared__ float dbl[REGION * 24];      // 9.2 KB [region_row][0:8=dt 8:16=B 16:24=C]
  const int f = blockIdx.y;
  const int s = slot[f];
  if (s < 0) return;
  const int c0 = blockIdx.x * CHUNK;
  const int r0 = c0 - RHALO;              // region start (may be negative)
  const int tid = threadIdx.x;
  const int c = tid & 127;                // channel
  const int half = tid >> 7;              // 0 = fwd waves, 1 = bwd waves
  const size_t rowbase = (size_t)s * T_TOK;
  const float4 cw = *(const float4*)(conv_w + c * 4);
  const float cb = conv_b[c];

  auto ldx = [&](int t) -> float {
    return (t >= 0 && t < T_TOK) ? xipre[(rowbase + t) * C_CH + c] : 0.0f;
  };

  // ---- stage dbl region slice: 96 rows x 24 floats = 576 float4 ----
  {
    const long grow = ((long)rowbase + r0) * 24;
    const int lo  = (r0 < 0) ? (-r0) * 6 : 0;
    const int hi  = (r0 + REGION > T_TOK) ? (T_TOK - r0) * 6 : REGION * 6;
    #pragma unroll
    for (int i = 0; i < 3; ++i) {
      const int idx = tid + i * 256;
      if (idx >= lo && idx < hi)
        *(float4*)&dbl[idx * 4] = *(const float4*)&dbl_g[grow + (long)idx * 4];
    }
  }
  __syncthreads();

  // ---- Scan setup ----
  float dw[8], Ac[8];
  const float* Alog = half ? A_log_b : A_log_f;
  #pragma unroll
  for (int r = 0; r < 8; ++r) dw[r] = dt_proj_w[r * C_CH + c];
  #pragma unroll
  for (int n = 0; n < NSTATE; ++n) Ac[n] = -expf(Alog[c * NSTATE + n]);
  const float bias = dt_proj_b[c];
  const float Dd = half ? D_b[c] : D_f[c];
  float h[8] = {0, 0, 0, 0, 0, 0, 0, 0};

  // fast-decay eligibility: Ac[n] == (n+1)*Ac[0] (holds for this problem's A)
  const float a0 = Ac[0];
  int okl = 1;
  #pragma unroll
  for (int n = 1; n < NSTATE; ++n)
    okl &= (fabsf(Ac[n] - (float)(n + 1) * a0) <= 1e-4f * fabsf(Ac[n])) ? 1 : 0;
  const bool fastA = (__all(okl) != 0);   // wave-uniform

  auto decay8 = [&](float dlt, float* dA) {
    if (fastA) {
      const float e1 = __expf(dlt * a0);
      const float e2 = e1 * e1, e3 = e2 * e1, e4 = e2 * e2;
      dA[0] = e1; dA[1] = e2; dA[2] = e3; dA[3] = e4;
      dA[4] = e4 * e1; dA[5] = e4 * e2; dA[6] = e4 * e3; dA[7] = e4 * e4;
    } else {
      #pragma unroll
      for (int n = 0; n < NSTATE; ++n) dA[n] = __expf(dlt * Ac[n]);
    }
  };

  if (half == 0) {
    // forward: t from tb to c0+CHUNK-1
    const int tb = (r0 < 0) ? 0 : r0;
    const int steps = c0 + CHUNK - tb;       // 64 or 32
    const int outg0 = (c0 - tb) >> 3;        // first output group (4 or 0)
    const int ng = steps >> 3;
    float xm1 = ldx(tb - 1), xm2 = ldx(tb - 2), xm3 = ldx(tb - 3);
    for (int g = 0; g < ng; ++g) {
      const int t0 = tb + g * 8;
      const bool out = (g >= outg0);
      float pg[8], wg[8];
      #pragma unroll
      for (int j = 0; j < 8; ++j) {
        const size_t gi = (rowbase + t0 + j) * C_CH + c;
        pg[j] = xipre[gi];
        wg[j] = out ? wbuf[gi] : 0.0f;
      }
      #pragma unroll
      for (int j = 0; j < 8; ++j) {
        const int t = t0 + j;
        const int p = t - r0;
        const float cur = pg[j];
        const float sum = cw.x * xm3 + cw.y * xm2 + cw.z * xm1 + cw.w * cur + cb;
        const float xiv = fast_silu(sum);
        xm3 = xm2; xm2 = xm1; xm1 = cur;
        const float4 d0 = *(const float4*)&dbl[p * 24];
        const float4 d1 = *(const float4*)&dbl[p * 24 + 4];
        float pre = bias;
        pre += d0.x * dw[0] + d0.y * dw[1] + d0.z * dw[2] + d0.w * dw[3];
        pre += d1.x * dw[4] + d1.y * dw[5] + d1.z * dw[6] + d1.w * dw[7];
        const float dlt = fmaxf(pre, 0.0f) + __logf(1.0f + __expf(-fabsf(pre)));
        const float u = dlt * xiv;
        const float4 b0 = *(const float4*)&dbl[p * 24 + 8];
        const float4 b1 = *(const float4*)&dbl[p * 24 + 12];
        float dA[8];
        decay8(dlt, dA);
        h[0] = dA[0] * h[0] + u * b0.x;
        h[1] = dA[1] * h[1] + u * b0.y;
        h[2] = dA[2] * h[2] + u * b0.z;
        h[3] = dA[3] * h[3] + u * b0.w;
        h[4] = dA[4] * h[4] + u * b1.x;
        h[5] = dA[5] * h[5] + u * b1.y;
        h[6] = dA[6] * h[6] + u * b1.z;
        h[7] = dA[7] * h[7] + u * b1.w;
        if (out) {
          const float4 cc0 = *(const float4*)&dbl[p * 24 + 16];
          const float4 cc1 = *(const float4*)&dbl[p * 24 + 20];
          float y = xiv * Dd;
          y += h[0] * cc0.x + h[1] * cc0.y + h[2] * cc0.z + h[3] * cc0.w;
          y += h[4] * cc1.x + h[5] * cc1.y + h[6] * cc1.z + h[7] * cc1.w;
          float contrib = y * wg[j];
          contrib += __shfl_xor(contrib, 1);
          contrib += __shfl_xor(contrib, 2);
          contrib += __shfl_xor(contrib, 4);
          contrib += __shfl_xor(contrib, 8);
          contrib += __shfl_xor(contrib, 16);
          contrib += __shfl_xor(contrib, 32);
          if ((tid & 63) == 0) atomicAdd(&logit[rowbase + t], contrib);
        }
      }
    }
  } else {
    // backward: t from te2-1 down to c0
    const int te2e = r0 + REGION;
    const int te2 = (te2e > T_TOK) ? T_TOK : te2e;
    const int steps = te2 - c0;              // 64 or 32
    const int outg0 = (te2 - (c0 + CHUNK)) >> 3;  // 4 or 0
    const int ng = steps >> 3;
    float w0 = ldx(te2 - 1), w1 = ldx(te2 - 2), w2 = ldx(te2 - 3), w3 = ldx(te2 - 4);
    for (int g = 0; g < ng; ++g) {
      const int t0 = te2 - 1 - g * 8;
      const bool out = (g >= outg0);
      float nv[8], wg[8];
      #pragma unroll
      for (int j = 0; j < 8; ++j) {
        nv[j] = ldx(t0 - 4 - j);
        wg[j] = out ? wbuf[(rowbase + t0 - j) * C_CH + c] : 0.0f;
      }
      #pragma unroll
      for (int j = 0; j < 8; ++j) {
        const int t = t0 - j;
        const int p = t - r0;
        const float sum = cw.x * w3 + cw.y * w2 + cw.z * w1 + cw.w * w0 + cb;
        const float xiv = fast_silu(sum);
        w0 = w1; w1 = w2; w2 = w3; w3 = nv[j];
        const float4 d0 = *(const float4*)&dbl[p * 24];
        const float4 d1 = *(const float4*)&dbl[p * 24 + 4];
        float pre = bias;
        pre += d0.x * dw[0] + d0.y * dw[1] + d0.z * dw[2] + d0.w * dw[3];
        pre += d1.x * dw[4] + d1.y * dw[5] + d1.z * dw[6] + d1.w * dw[7];
        const float dlt = fmaxf(pre, 0.0f) + __logf(1.0f + __expf(-fabsf(pre)));
        const float u = dlt * xiv;
        const float4 b0 = *(const float4*)&dbl[p * 24 + 8];
        const float4 b1 = *(const float4*)&dbl[p * 24 + 12];
        float dA[8];
        decay8(dlt, dA);
        h[0] = dA[0] * h[0] + u * b0.x;
        h[1] = dA[1] * h[1] + u * b0.y;
        h[2] = dA[2] * h[2] + u * b0.z;
        h[3] = dA[3] * h[3] + u * b0.w;
        h[4] = dA[4] * h[4] + u * b1.x;
        h[5] = dA[5] * h[5] + u * b1.y;
        h[6] = dA[6] * h[6] + u * b1.z;
        h[7] = dA[7] * h[7] + u * b1.w;
        if (out) {
          const float4 cc0 = *(const float4*)&dbl[p * 24 + 16];
          const float4 cc1 = *(const float4*)&dbl[p * 24 + 20];
          float y = xiv * Dd;
          y += h[0] * cc0.x + h[1] * cc0.y + h[2] * cc0.z + h[3] * cc0.w;
          y += h[4] * cc1.x + h[5] * cc1.y + h[6] * cc1.z + h[7] * cc1.w;
          float contrib = y * wg[j];
          contrib += __shfl_xor(contrib, 1);
          contrib += __shfl_xor(contrib, 2);
          contrib += __shfl_xor(contrib, 4);
          contrib += __shfl_xor(contrib, 8);
          contrib += __shfl_xor(contrib, 16);
          contrib += __shfl_xor(contrib, 32);
          if ((tid & 63) == 0) atomicAdd(&logit[rowbase + t], contrib);
        }
      }
    }
  }
}

// ---------------------------------------------------------------------------
// K4: threshold (sigmoid(lg)>0.5 <=> lg>0, exact) + 3x3 max pool. ego -> 1.
// ---------------------------------------------------------------------------
__global__ __launch_bounds__(128) void k4_pool(
    const float* __restrict__ logit, const int* __restrict__ slot,
    float* __restrict__ out)
{
  const int w = threadIdx.x;
  if (w >= W_IMG) return;
  const int hh = blockIdx.x;
  const int f = blockIdx.y;
  const int s = slot[f];
  float m = 0.0f;
  if (s < 0) {
    m = 1.0f;
  } else {
    for (int dh = -1; dh <= 1; ++dh) {
      const int h2 = hh + dh;
      if (h2 < 0 || h2 >= H_IMG) continue;
      for (int dw = -1; dw <= 1; ++dw) {
        const int w2 = w + dw;
        if (w2 < 0 || w2 >= W_IMG) continue;
        if (logit[(size_t)s * T_TOK + h2 * W_IMG + w2] > 0.0f) m = 1.0f;
      }
    }
  }
  out[(size_t)f * T_TOK + hh * W_IMG + w] = m;
}

// ---------------------------------------------------------------------------
extern "C" void kernel_launch(void* const* d_in, const int* in_sizes, int n_in,
                              void* d_out, int out_size, void* d_ws, size_t ws_size,
                              hipStream_t stream) {
  const float* feats      = (const float*)d_in[0];
  const float* in_proj    = (const float*)d_in[1];
  const float* conv_w     = (const float*)d_in[2];
  const float* conv_b     = (const float*)d_in[3];
  const float* x_proj_w   = (const float*)d_in[4];
  const float* dt_proj_w  = (const float*)d_in[5];
  const float* dt_proj_b  = (const float*)d_in[6];
  const float* A_log_f    = (const float*)d_in[7];
  const float* A_log_b    = (const float*)d_in[8];
  const float* D_f        = (const float*)d_in[9];
  const float* D_b        = (const float*)d_in[10];
  const float* out_proj_w = (const float*)d_in[11];
  const float* rms_w      = (const float*)d_in[12];
  const float* mlp_w      = (const float*)d_in[13];
  const float* mlp_b      = (const float*)d_in[14];
  const int*   rec        = (const int*)d_in[15];   // int32! (jax downcasts int64)

  const int N = in_sizes[0] / (C_CH * T_TOK);
  const int n_groups = in_sizes[15];
  int S = N - n_groups;
  if (S < 1) S = 1;

  // workspace carve-up
  char* p = (char*)d_ws;
  float* vvec  = (float*)p; p += 1024;
  int*   slot  = (int*)p;   p += ((N * 4 + 255) / 256) * 256;
  float* logit = (float*)p; p += (size_t)S * T_TOK * 4;
  float* xipre = (float*)p; p += (size_t)S * T_TOK * C_CH * 4;
  float* wA    = (float*)p; p += (size_t)S * T_TOK * C_CH * 4;
  float* dblg  = (float*)p; p += (size_t)S * T_TOK * 24 * 4;
  (void)ws_size; (void)n_in; (void)out_size;

  k0_setup<<<1, 128, 0, stream>>>(rec, n_groups, N, out_proj_w, mlp_w, vvec, slot);
  k1_gemm<<<dim3(T_TOK / 64, N), 256, 0, stream>>>(
      feats, in_proj, rms_w, mlp_w, mlp_b, vvec, slot, xipre, wA, logit);
  k2_convproj<<<dim3(T_TOK / 64, N), 256, 0, stream>>>(
      xipre, conv_w, conv_b, x_proj_w, slot, dblg);
  k3_scan<<<dim3(T_TOK / CHUNK, N), 256, 0, stream>>>(
      xipre, wA, dblg, conv_w, conv_b, dt_proj_w, dt_proj_b,
      A_log_f, A_log_b, D_f, D_b, slot, logit);
  k4_pool<<<dim3(H_IMG, N), 128, 0, stream>>>(logit, slot, (float*)d_out);
}

// Round 6
// 311.102 us; speedup vs baseline: 1.1302x; 1.1144x over previous
//
#include <hip/hip_runtime.h>
#include <cstdint>
#include <cstddef>

#define C_CH 128
#define T_TOK 9216
#define H_IMG 96
#define W_IMG 96
#define NSTATE 8

// fused scan tiling: 64 output tokens, 32-token warm-up halo each direction.
// CHUNK=64 (halo ratio 1.5) + precomputed xi/delta: scan step is pure
// h-recurrence (dA,u h-independent -> ~1 FMA critical path per step).
#define CHUNK 64
#define RHALO 32
#define REGION (CHUNK + 2 * RHALO)   // 128

__device__ __forceinline__ float siluf_dev(float x) {
  return x / (1.0f + expf(-x));
}

__device__ __forceinline__ float fast_silu(float x) {
  // x * sigmoid(x) with native rcp; binary-thresholded output tolerates ~2ulp
  return __fdividef(x, 1.0f + __expf(-x));
}

// ---------------------------------------------------------------------------
// K0: slot assignment from record_len (int32!) + v = out_proj_w @ mlp_w
// ---------------------------------------------------------------------------
__global__ __launch_bounds__(128) void k0_setup(
    const int* __restrict__ rec, int n_groups, int N,
    const float* __restrict__ out_proj_w, const float* __restrict__ mlp_w,
    float* __restrict__ vvec, int* __restrict__ slot)
{
  const int tid = threadIdx.x;
  if (tid == 0) {
    int f = 0, sl = 0;
    for (int g = 0; g < n_groups; ++g) {
      const int L = rec[g];
      slot[f] = -1;                       // ego / single frame -> mask = 1
      for (int i = 1; i < L; ++i) slot[f + i] = sl++;
      f += L;
    }
  }
  if (tid < C_CH) {
    float acc = 0.0f;
    for (int j = 0; j < C_CH; ++j) acc += out_proj_w[tid * C_CH + j] * mlp_w[j];
    vvec[tid] = acc;
  }
}

// ---------------------------------------------------------------------------
// K1: rmsnorm + xz = xn @ in_proj  (M=64 token tile, K=128, N=256 in 4 chunks)
//     writes xi_pre[t][c], w[t][c] = 0.5*silu(z)*v[c], logit_init[t]
// B streamed from global (16 lanes/tc share an address -> HW broadcast;
// in_proj 128KB is L2-hot). rms_w folded into Asm. LDS 34.5 KB, 4 blocks/CU.
// ---------------------------------------------------------------------------
__global__ __launch_bounds__(256, 4) void k1_gemm(
    const float* __restrict__ feats, const float* __restrict__ in_proj,
    const float* __restrict__ rms_w, const float* __restrict__ mlp_w,
    const float* __restrict__ mlp_b, const float* __restrict__ vvec,
    const int* __restrict__ slot,
    float* __restrict__ xipre, float* __restrict__ wbuf,
    float* __restrict__ logit)
{
  __shared__ float Asm[C_CH * 64];   // A[k][t]  (raw x, then ir*rw-scaled)
  __shared__ float redA[256], redB[256], irS[64];
  const int f = blockIdx.y;
  const int s = slot[f];
  if (s < 0) return;
  const int m0 = blockIdx.x * 64;
  const int tid = threadIdx.x;

  // stage A: x[c][t], coalesced along t
  {
    const int c0 = tid >> 4;
    const int tq = (tid & 15) * 4;
    const float* src = feats + (size_t)f * C_CH * T_TOK + m0 + tq;
    #pragma unroll
    for (int i = 0; i < 8; ++i) {
      const int c = c0 + i * 16;
      const float4 x4 = *(const float4*)(src + (size_t)c * T_TOK);
      *(float4*)&Asm[c * 64 + tq] = x4;
    }
  }
  __syncthreads();
  // pre-pass: per-token rms + logit init (res . mlp_w + b), 4 threads/token
  {
    const int t = tid & 63;
    const int q = tid >> 6;
    float ssum = 0.0f, rm = 0.0f;
    for (int cc = q * 32; cc < q * 32 + 32; ++cc) {
      const float val = Asm[cc * 64 + t];
      ssum += val * val;
      rm += val * mlp_w[cc];
    }
    redA[tid] = ssum; redB[tid] = rm;
  }
  __syncthreads();
  if (tid < 64) {
    const int t = tid;
    const float ssum = redA[t] + redA[t + 64] + redA[t + 128] + redA[t + 192];
    const float rm   = redB[t] + redB[t + 64] + redB[t + 128] + redB[t + 192];
    const float ir = 1.0f / sqrtf(ssum * (1.0f / C_CH) + 1e-5f);
    logit[(size_t)s * T_TOK + m0 + t] = rm + mlp_b[0];
    irS[t] = ir;
  }
  __syncthreads();
  {
    const int t = tid & 63;
    const int q = tid >> 6;
    const float ir = irS[t];
    for (int cc = q * 32; cc < q * 32 + 32; ++cc)
      Asm[cc * 64 + t] = (Asm[cc * 64 + t] * ir) * rms_w[cc];
  }
  __syncthreads();

  const int ti = tid >> 4;   // 0..15 -> rows ti*4..+3
  const int tc = tid & 15;   // 0..15 -> cols tc*4..+3
  for (int chunk = 0; chunk < 4; ++chunk) {
    const int n0 = chunk * 64;
    const float* bp = in_proj + n0 + tc * 4;
    float acc[4][4];
    #pragma unroll
    for (int i = 0; i < 4; ++i)
      #pragma unroll
      for (int j = 0; j < 4; ++j) acc[i][j] = 0.0f;
    #pragma unroll 8
    for (int k = 0; k < C_CH; ++k) {
      const float4 a4 = *(const float4*)&Asm[k * 64 + ti * 4];
      const float4 b4 = *(const float4*)(bp + (size_t)k * 256);
      acc[0][0] += a4.x * b4.x; acc[0][1] += a4.x * b4.y; acc[0][2] += a4.x * b4.z; acc[0][3] += a4.x * b4.w;
      acc[1][0] += a4.y * b4.x; acc[1][1] += a4.y * b4.y; acc[1][2] += a4.y * b4.z; acc[1][3] += a4.y * b4.w;
      acc[2][0] += a4.z * b4.x; acc[2][1] += a4.z * b4.y; acc[2][2] += a4.z * b4.z; acc[2][3] += a4.z * b4.w;
      acc[3][0] += a4.w * b4.x; acc[3][1] += a4.w * b4.y; acc[3][2] += a4.w * b4.z; acc[3][3] += a4.w * b4.w;
    }
    if (chunk < 2) {
      const int cb = n0 + tc * 4;     // xi channel 0..127
      #pragma unroll
      for (int i = 0; i < 4; ++i) {
        const int t = m0 + ti * 4 + i;
        float4 o; o.x = acc[i][0]; o.y = acc[i][1]; o.z = acc[i][2]; o.w = acc[i][3];
        *(float4*)&xipre[((size_t)s * T_TOK + t) * C_CH + cb] = o;
      }
    } else {
      const int zc = (chunk - 2) * 64 + tc * 4;  // z channel 0..127
      const float4 v4 = *(const float4*)&vvec[zc];
      #pragma unroll
      for (int i = 0; i < 4; ++i) {
        const int t = m0 + ti * 4 + i;
        float4 o;
        o.x = 0.5f * siluf_dev(acc[i][0]) * v4.x;
        o.y = 0.5f * siluf_dev(acc[i][1]) * v4.y;
        o.z = 0.5f * siluf_dev(acc[i][2]) * v4.z;
        o.w = 0.5f * siluf_dev(acc[i][3]) * v4.w;
        *(float4*)&wbuf[((size_t)s * T_TOK + t) * C_CH + zc] = o;
      }
    }
  }
}

// ---------------------------------------------------------------------------
// K2: conv+silu -> xi_g[t][c]; projection -> B,C -> bc_g[t][16] and dt -> LDS;
// delta[t][c] = softplus(dt . dt_proj_w[:,c] + b[c]) -> delta_g[t][c].
// All arithmetic orders identical to the old in-k3 formulas -> bit-identical.
// LDS: xibuf 33 KB + dtb 2 KB = 35 KB, 4 blocks/CU.
// ---------------------------------------------------------------------------
__global__ __launch_bounds__(256, 4) void k2_convproj(
    const float* __restrict__ xipre,
    const float* __restrict__ conv_w, const float* __restrict__ conv_b,
    const float* __restrict__ x_proj_w,
    const float* __restrict__ dt_proj_w, const float* __restrict__ dt_proj_b,
    const int* __restrict__ slot,
    float* __restrict__ xi_g, float* __restrict__ delta_g,
    float* __restrict__ bc_g)
{
  __shared__ float xibuf[64 * 129];   // 33 KB
  __shared__ float dtb[64 * 8];       // 2 KB: dt rows per token
  const int f = blockIdx.y;
  const int s = slot[f];
  if (s < 0) return;
  const int m0 = blockIdx.x * 64;
  const int tid = threadIdx.x;
  const int c = tid & 127;
  const int half = tid >> 7;
  const size_t rowbase = (size_t)s * T_TOK;
  const float4 cw = *(const float4*)(conv_w + c * 4);
  const float cb = conv_b[c];

  auto ldx = [&](int t) -> float {
    return (t >= 0) ? xipre[(rowbase + t) * C_CH + c] : 0.0f;   // t < T always here
  };

  // ---- conv + silu: 32 rows per thread-half; store to LDS + xi_g ----
  {
    const int t0 = m0 + half * 32;
    float xm1 = ldx(t0 - 1), xm2 = ldx(t0 - 2), xm3 = ldx(t0 - 3);
    #pragma unroll
    for (int i = 0; i < 32; ++i) {
      const float cur = ldx(t0 + i);
      const float sum = cw.x * xm3 + cw.y * xm2 + cw.z * xm1 + cw.w * cur + cb;
      const float xiv = fast_silu(sum);
      xibuf[(half * 32 + i) * 129 + c] = xiv;
      xi_g[(rowbase + t0 + i) * C_CH + c] = xiv;
      xm3 = xm2; xm2 = xm1; xm1 = cur;
    }
  }
  __syncthreads();
  // ---- projection 128->24: lane=token, wave handles 6 outputs ----
  {
    const int q6 = __builtin_amdgcn_readfirstlane(tid >> 6) * 6;  // wave's out base
    const int tok = tid & 63;
    float acc[6] = {0, 0, 0, 0, 0, 0};
    for (int cc = 0; cc < C_CH; ++cc) {
      const float xv = xibuf[tok * 129 + cc];
      #pragma unroll
      for (int jj = 0; jj < 6; ++jj)
        acc[jj] += xv * x_proj_w[cc * 24 + q6 + jj];   // scalar (uniform idx)
    }
    #pragma unroll
    for (int jj = 0; jj < 6; ++jj) {
      const int o = q6 + jj;                // wave-uniform
      if (o < 8) dtb[tok * 8 + o] = acc[jj];
      else       bc_g[(rowbase + m0 + tok) * 16 + (o - 8)] = acc[jj];
    }
  }
  __syncthreads();
  // ---- delta: lane=channel, 32 tokens per thread-half ----
  {
    float dw[8];
    #pragma unroll
    for (int r = 0; r < 8; ++r) dw[r] = dt_proj_w[r * C_CH + c];
    const float bias = dt_proj_b[c];
    for (int i = 0; i < 32; ++i) {
      const int tok = half * 32 + i;
      const float4 d0 = *(const float4*)&dtb[tok * 8];      // broadcast
      const float4 d1 = *(const float4*)&dtb[tok * 8 + 4];
      float pre = bias;
      pre += d0.x * dw[0] + d0.y * dw[1] + d0.z * dw[2] + d0.w * dw[3];
      pre += d1.x * dw[4] + d1.y * dw[5] + d1.z * dw[6] + d1.w * dw[7];
      const float dlt = fmaxf(pre, 0.0f) + __logf(1.0f + __expf(-fabsf(pre)));
      delta_g[(rowbase + m0 + tok) * C_CH + c] = dlt;
    }
  }
}

// ---------------------------------------------------------------------------
// K3_scan: pure bidirectional h-recurrence. Block = 256 threads = one
// 64-token chunk, waves 0-1 fwd / waves 2-3 bwd. Region [c0-32, c0+96),
// 96 steps per direction. Inputs xi/delta precomputed -> dA,u for a whole
// 8-step group are h-independent (computable in parallel); critical path
// per step ~ 1 FMA. B,C staged from bc_g (128 rows x 16 floats = 8.2 KB LDS).
// Arithmetic order identical to R3/R5 -> bit-identical logits.
// ---------------------------------------------------------------------------
__global__ __launch_bounds__(256, 4) void k3_scan(
    const float* __restrict__ xi_g, const float* __restrict__ delta_g,
    const float* __restrict__ wbuf, const float* __restrict__ bc_g,
    const float* __restrict__ A_log_f, const float* __restrict__ A_log_b,
    const float* __restrict__ D_f, const float* __restrict__ D_b,
    const int* __restrict__ slot, float* __restrict__ logit)
{
  __shared__ float bc[REGION * 16];       // 8.2 KB [region_row][0:8=B 8:16=C]
  const int f = blockIdx.y;
  const int s = slot[f];
  if (s < 0) return;
  const int c0 = blockIdx.x * CHUNK;
  const int r0 = c0 - RHALO;              // region start (may be negative)
  const int tid = threadIdx.x;
  const int c = tid & 127;                // channel
  const int half = tid >> 7;              // 0 = fwd waves, 1 = bwd waves
  const size_t rowbase = (size_t)s * T_TOK;

  // ---- stage B,C region slice: 128 rows x 16 floats = 512 float4 ----
  {
    const long grow = ((long)rowbase + r0) * 16;
    const int lo  = (r0 < 0) ? (-r0) * 4 : 0;
    const int hi  = (r0 + REGION > T_TOK) ? (T_TOK - r0) * 4 : REGION * 4;
    #pragma unroll
    for (int i = 0; i < 2; ++i) {
      const int idx = tid + i * 256;
      if (idx >= lo && idx < hi)
        *(float4*)&bc[idx * 4] = *(const float4*)&bc_g[grow + (long)idx * 4];
    }
  }
  __syncthreads();

  // ---- Scan setup ----
  float Ac[8];
  const float* Alog = half ? A_log_b : A_log_f;
  #pragma unroll
  for (int n = 0; n < NSTATE; ++n) Ac[n] = -expf(Alog[c * NSTATE + n]);
  const float Dd = half ? D_b[c] : D_f[c];
  float h[8] = {0, 0, 0, 0, 0, 0, 0, 0};

  // fast-decay eligibility: Ac[n] == (n+1)*Ac[0] (holds for this problem's A)
  const float a0 = Ac[0];
  int okl = 1;
  #pragma unroll
  for (int n = 1; n < NSTATE; ++n)
    okl &= (fabsf(Ac[n] - (float)(n + 1) * a0) <= 1e-4f * fabsf(Ac[n])) ? 1 : 0;
  const bool fastA = (__all(okl) != 0);   // wave-uniform

  auto decay8 = [&](float dlt, float* dA) {
    if (fastA) {
      const float e1 = __expf(dlt * a0);
      const float e2 = e1 * e1, e3 = e2 * e1, e4 = e2 * e2;
      dA[0] = e1; dA[1] = e2; dA[2] = e3; dA[3] = e4;
      dA[4] = e4 * e1; dA[5] = e4 * e2; dA[6] = e4 * e3; dA[7] = e4 * e4;
    } else {
      #pragma unroll
      for (int n = 0; n < NSTATE; ++n) dA[n] = __expf(dlt * Ac[n]);
    }
  };

  if (half == 0) {
    // forward: t from tb to c0+CHUNK-1
    const int tb = (r0 < 0) ? 0 : r0;
    const int outg0 = (c0 - tb) >> 3;        // first output group (4 or 0)
    const int ng = (c0 + CHUNK - tb) >> 3;   // 12 or 8
    for (int g = 0; g < ng; ++g) {
      const int t0 = tb + g * 8;
      const bool out = (g >= outg0);
      float xg[8], dg[8], wg[8];
      #pragma unroll
      for (int j = 0; j < 8; ++j) {
        const size_t gi = (rowbase + t0 + j) * C_CH + c;
        xg[j] = xi_g[gi];
        dg[j] = delta_g[gi];
        wg[j] = out ? wbuf[gi] : 0.0f;
      }
      #pragma unroll
      for (int j = 0; j < 8; ++j) {
        const int t = t0 + j;
        const int p = t - r0;
        const float dlt = dg[j];
        const float xiv = xg[j];
        const float u = dlt * xiv;
        const float4 b0 = *(const float4*)&bc[p * 16];
        const float4 b1 = *(const float4*)&bc[p * 16 + 4];
        float dA[8];
        decay8(dlt, dA);
        h[0] = dA[0] * h[0] + u * b0.x;
        h[1] = dA[1] * h[1] + u * b0.y;
        h[2] = dA[2] * h[2] + u * b0.z;
        h[3] = dA[3] * h[3] + u * b0.w;
        h[4] = dA[4] * h[4] + u * b1.x;
        h[5] = dA[5] * h[5] + u * b1.y;
        h[6] = dA[6] * h[6] + u * b1.z;
        h[7] = dA[7] * h[7] + u * b1.w;
        if (out) {
          const float4 cc0 = *(const float4*)&bc[p * 16 + 8];
          const float4 cc1 = *(const float4*)&bc[p * 16 + 12];
          float y = xiv * Dd;
          y += h[0] * cc0.x + h[1] * cc0.y + h[2] * cc0.z + h[3] * cc0.w;
          y += h[4] * cc1.x + h[5] * cc1.y + h[6] * cc1.z + h[7] * cc1.w;
          float contrib = y * wg[j];
          contrib += __shfl_xor(contrib, 1);
          contrib += __shfl_xor(contrib, 2);
          contrib += __shfl_xor(contrib, 4);
          contrib += __shfl_xor(contrib, 8);
          contrib += __shfl_xor(contrib, 16);
          contrib += __shfl_xor(contrib, 32);
          if ((tid & 63) == 0) atomicAdd(&logit[rowbase + t], contrib);
        }
      }
    }
  } else {
    // backward: t from te2-1 down to c0
    const int te2e = r0 + REGION;
    const int te2 = (te2e > T_TOK) ? T_TOK : te2e;
    const int outg0 = (te2 - (c0 + CHUNK)) >> 3;  // 4 or 0
    const int ng = (te2 - c0) >> 3;               // 12 or 8
    for (int g = 0; g < ng; ++g) {
      const int t0 = te2 - 1 - g * 8;
      const bool out = (g >= outg0);
      float xg[8], dg[8], wg[8];
      #pragma unroll
      for (int j = 0; j < 8; ++j) {
        const size_t gi = (rowbase + t0 - j) * C_CH + c;
        xg[j] = xi_g[gi];
        dg[j] = delta_g[gi];
        wg[j] = out ? wbuf[gi] : 0.0f;
      }
      #pragma unroll
      for (int j = 0; j < 8; ++j) {
        const int t = t0 - j;
        const int p = t - r0;
        const float dlt = dg[j];
        const float xiv = xg[j];
        const float u = dlt * xiv;
        const float4 b0 = *(const float4*)&bc[p * 16];
        const float4 b1 = *(const float4*)&bc[p * 16 + 4];
        float dA[8];
        decay8(dlt, dA);
        h[0] = dA[0] * h[0] + u * b0.x;
        h[1] = dA[1] * h[1] + u * b0.y;
        h[2] = dA[2] * h[2] + u * b0.z;
        h[3] = dA[3] * h[3] + u * b0.w;
        h[4] = dA[4] * h[4] + u * b1.x;
        h[5] = dA[5] * h[5] + u * b1.y;
        h[6] = dA[6] * h[6] + u * b1.z;
        h[7] = dA[7] * h[7] + u * b1.w;
        if (out) {
          const float4 cc0 = *(const float4*)&bc[p * 16 + 8];
          const float4 cc1 = *(const float4*)&bc[p * 16 + 12];
          float y = xiv * Dd;
          y += h[0] * cc0.x + h[1] * cc0.y + h[2] * cc0.z + h[3] * cc0.w;
          y += h[4] * cc1.x + h[5] * cc1.y + h[6] * cc1.z + h[7] * cc1.w;
          float contrib = y * wg[j];
          contrib += __shfl_xor(contrib, 1);
          contrib += __shfl_xor(contrib, 2);
          contrib += __shfl_xor(contrib, 4);
          contrib += __shfl_xor(contrib, 8);
          contrib += __shfl_xor(contrib, 16);
          contrib += __shfl_xor(contrib, 32);
          if ((tid & 63) == 0) atomicAdd(&logit[rowbase + t], contrib);
        }
      }
    }
  }
}

// ---------------------------------------------------------------------------
// K4: threshold (sigmoid(lg)>0.5 <=> lg>0, exact) + 3x3 max pool. ego -> 1.
// ---------------------------------------------------------------------------
__global__ __launch_bounds__(128) void k4_pool(
    const float* __restrict__ logit, const int* __restrict__ slot,
    float* __restrict__ out)
{
  const int w = threadIdx.x;
  if (w >= W_IMG) return;
  const int hh = blockIdx.x;
  const int f = blockIdx.y;
  const int s = slot[f];
  float m = 0.0f;
  if (s < 0) {
    m = 1.0f;
  } else {
    for (int dh = -1; dh <= 1; ++dh) {
      const int h2 = hh + dh;
      if (h2 < 0 || h2 >= H_IMG) continue;
      for (int dw = -1; dw <= 1; ++dw) {
        const int w2 = w + dw;
        if (w2 < 0 || w2 >= W_IMG) continue;
        if (logit[(size_t)s * T_TOK + h2 * W_IMG + w2] > 0.0f) m = 1.0f;
      }
    }
  }
  out[(size_t)f * T_TOK + hh * W_IMG + w] = m;
}

// ---------------------------------------------------------------------------
extern "C" void kernel_launch(void* const* d_in, const int* in_sizes, int n_in,
                              void* d_out, int out_size, void* d_ws, size_t ws_size,
                              hipStream_t stream) {
  const float* feats      = (const float*)d_in[0];
  const float* in_proj    = (const float*)d_in[1];
  const float* conv_w     = (const float*)d_in[2];
  const float* conv_b     = (const float*)d_in[3];
  const float* x_proj_w   = (const float*)d_in[4];
  const float* dt_proj_w  = (const float*)d_in[5];
  const float* dt_proj_b  = (const float*)d_in[6];
  const float* A_log_f    = (const float*)d_in[7];
  const float* A_log_b    = (const float*)d_in[8];
  const float* D_f        = (const float*)d_in[9];
  const float* D_b        = (const float*)d_in[10];
  const float* out_proj_w = (const float*)d_in[11];
  const float* rms_w      = (const float*)d_in[12];
  const float* mlp_w      = (const float*)d_in[13];
  const float* mlp_b      = (const float*)d_in[14];
  const int*   rec        = (const int*)d_in[15];   // int32! (jax downcasts int64)

  const int N = in_sizes[0] / (C_CH * T_TOK);
  const int n_groups = in_sizes[15];
  int S = N - n_groups;
  if (S < 1) S = 1;

  // workspace carve-up (~137 MB at S=7)
  char* p = (char*)d_ws;
  float* vvec  = (float*)p; p += 1024;
  int*   slot  = (int*)p;   p += ((N * 4 + 255) / 256) * 256;
  float* logit = (float*)p; p += (size_t)S * T_TOK * 4;
  float* xipre = (float*)p; p += (size_t)S * T_TOK * C_CH * 4;
  float* wA    = (float*)p; p += (size_t)S * T_TOK * C_CH * 4;
  float* xig   = (float*)p; p += (size_t)S * T_TOK * C_CH * 4;
  float* dltg  = (float*)p; p += (size_t)S * T_TOK * C_CH * 4;
  float* bcg   = (float*)p; p += (size_t)S * T_TOK * 16 * 4;
  (void)ws_size; (void)n_in; (void)out_size;

  k0_setup<<<1, 128, 0, stream>>>(rec, n_groups, N, out_proj_w, mlp_w, vvec, slot);
  k1_gemm<<<dim3(T_TOK / 64, N), 256, 0, stream>>>(
      feats, in_proj, rms_w, mlp_w, mlp_b, vvec, slot, xipre, wA, logit);
  k2_convproj<<<dim3(T_TOK / 64, N), 256, 0, stream>>>(
      xipre, conv_w, conv_b, x_proj_w, dt_proj_w, dt_proj_b, slot,
      xig, dltg, bcg);
  k3_scan<<<dim3(T_TOK / CHUNK, N), 256, 0, stream>>>(
      xig, dltg, wA, bcg, A_log_f, A_log_b, D_f, D_b, slot, logit);
  k4_pool<<<dim3(H_IMG, N), 128, 0, stream>>>(logit, slot, (float*)d_out);
}